// Round 8
// baseline (360.425 us; speedup 1.0000x reference)
//
#include <hip/hip_runtime.h>
#include <hip/hip_bf16.h>

// MHA: B=256, T=256, E=384, H=6, D=64.  fp32 in/out, bf16 MFMA internally.
//
//   prep+xcast: fused (round 7): blocks [0,12288) cast x->bf16,
//          blocks [12288,14592) repack weights.
//   qkv:   ROUND 8: BK=32 QUAD-buffered LDS (4 x 20 KB = 80 KB, still 2 blk/CU)
//          -> prefetch distance 3 phases (~3x latency cover vs round-6's dbuf),
//          ONE raw s_barrier per step, counted vmcnt(10/5/0). No setprio
//          (round-7: setprio on qkv = -6 us). Swizzle re-derived for 4-slot
//          rows: phys = logical ^ ((row>>1)&3), both-sides (T21).
//   attn:  one block per (b,h); K/V staged in LDS once; barrier-free causal
//          balance {w,7-w,8+w,15-w}; Q hoisted pre-barrier; setprio (round-7).
//   proj:  round-7 form (BK=64 dbuf counted vmcnt + setprio).

#define Bn 256
#define Tn 256
#define En 384
#define Hn 6
#define Dn 64

typedef __bf16 bf16x8 __attribute__((ext_vector_type(8)));
typedef float f32x4 __attribute__((ext_vector_type(4)));
typedef unsigned short u16x8 __attribute__((ext_vector_type(8)));

static __device__ __forceinline__ unsigned short f2bf(float f) {
    unsigned int u = __builtin_bit_cast(unsigned int, f);
    u += 0x7fffu + ((u >> 16) & 1u);   // RNE
    return (unsigned short)(u >> 16);
}

static __device__ __forceinline__ f32x4 mfma16(bf16x8 a, bf16x8 b, f32x4 c) {
    return __builtin_amdgcn_mfma_f32_16x16x32_bf16(a, b, c, 0, 0, 0);
}

// async global->LDS, 16 B per lane. LDS dest = wave-uniform base + lane*16.
static __device__ __forceinline__ void glds16(const unsigned short* g, unsigned short* l) {
    __builtin_amdgcn_global_load_lds(
        (const __attribute__((address_space(1))) unsigned int*)g,
        (__attribute__((address_space(3))) unsigned int*)l, 16, 0, 0);
}

// ---------------------------------------------------------------- prep + xcast (fused)
__global__ __launch_bounds__(256) void prep_xcast_kernel(
    const float* __restrict__ wq, const float* __restrict__ wk,
    const float* __restrict__ wv, const float* __restrict__ wp,
    const float* __restrict__ x,
    unsigned short* __restrict__ wt, unsigned short* __restrict__ wpt,
    unsigned short* __restrict__ xb) {
    const int bid = blockIdx.x;
    if (bid < 12288) {
        size_t i = ((size_t)bid * 256 + threadIdx.x) * 8;
        float4 f0 = *(const float4*)(x + i);
        float4 f1 = *(const float4*)(x + i + 4);
        u16x8 p;
        p[0] = f2bf(f0.x); p[1] = f2bf(f0.y); p[2] = f2bf(f0.z); p[3] = f2bf(f0.w);
        p[4] = f2bf(f1.x); p[5] = f2bf(f1.y); p[6] = f2bf(f1.z); p[7] = f2bf(f1.w);
        *(u16x8*)(xb + i) = p;
    } else {
        const int NW = 3 * Hn * Dn * En;      // 442368
        const int NP = En * En;               // 147456
        int idx = (bid - 12288) * 256 + threadIdx.x;
        if (idx < NW) {
            int e = idx % En;
            int d = (idx / En) % Dn;
            int h = (idx / (En * Dn)) % Hn;
            int t = idx / (En * Dn * Hn);
            const float* src = (t == 0) ? wq : (t == 1) ? wk : wv;
            wt[idx] = f2bf(src[(h * En + e) * Dn + d]);
        } else if (idx < NW + NP) {
            int j = idx - NW;
            int k = j % En;
            int n = j / En;
            wpt[j] = f2bf(wp[k * En + n]);
        }
    }
}

// ---------------------------------------------------------------- QKV projection (merged)
// grid 3072 (flattened): bijective XCD swizzle; logical order = head-fast.
// Tile 128x192, 4 waves 2x2, wave 64x96 (acc[4][6]).
// Quad-buffered BK=32: chunk = 16 rows x 32 cols (1 KB). lane l -> row l>>2,
// phys 8-elem slot l&3; source logical slot j = (l&3) ^ ((l>>3)&3).
// Read phys slot = quad ^ ((l16>>1)&3)  (both-sides XOR, 0-conflict floor).
// Per wave per buffer: 2 A + 3 B = 5 loads. Steady-state wait: vmcnt(10).
__global__ __launch_bounds__(256) void qkv_gemm(
    const unsigned short* __restrict__ xb, const unsigned short* __restrict__ wt,
    unsigned short* __restrict__ Qo, unsigned short* __restrict__ Ko,
    unsigned short* __restrict__ Vt) {
    __shared__ unsigned short As[4][128][32];   // 32 KB
    __shared__ unsigned short Bs[4][192][32];   // 48 KB  (80 KB total, 2 blk/CU)

    const int bid = blockIdx.x;
    const int swz = (bid & 7) * 384 + (bid >> 3);   // 3072/8 = 384, bijective
    const int h = swz % Hn;
    const int m0 = (swz / Hn) * 128;

    const int tid = threadIdx.x;
    const int wave = tid >> 6, lane = tid & 63;
    const int quad = lane >> 4, l16 = lane & 15;
    const int mw = (wave >> 1) * 64, nw = (wave & 1) * 96;

    f32x4 acc[4][6];
#pragma unroll
    for (int i = 0; i < 4; ++i)
#pragma unroll
        for (int j = 0; j < 6; ++j) acc[i][j] = (f32x4){0.f, 0.f, 0.f, 0.f};

    const int lrow = lane >> 2;                        // 0..15 within chunk
    const int js = (lane & 3) ^ ((lane >> 3) & 3);     // pre-swizzled source slot

    // A: 2 chunks/wave, rows wave*32 + i*16 + lrow
    const unsigned short* ga[2];
#pragma unroll
    for (int i = 0; i < 2; ++i)
        ga[i] = xb + (size_t)(m0 + wave * 32 + i * 16 + lrow) * En + js * 8;
    // B: 3 chunks/wave, n = wave*48 + i*16 + lrow; row n of [wq|wk|wv] pack
    const unsigned short* gb[3];
#pragma unroll
    for (int i = 0; i < 3; ++i) {
        int n = wave * 48 + i * 16 + lrow;
        gb[i] = wt + (size_t)(((n >> 6) * Hn + h) * Dn + (n & 63)) * En + js * 8;
    }

#define QKV_STAGE(buf, koff)                                              \
    do {                                                                  \
        glds16(ga[0] + (koff), &As[buf][wave * 32][0]);                   \
        glds16(ga[1] + (koff), &As[buf][wave * 32 + 16][0]);              \
        glds16(gb[0] + (koff), &Bs[buf][wave * 48][0]);                   \
        glds16(gb[1] + (koff), &Bs[buf][wave * 48 + 16][0]);              \
        glds16(gb[2] + (koff), &Bs[buf][wave * 48 + 32][0]);              \
    } while (0)

    QKV_STAGE(0, 0);
    QKV_STAGE(1, 32);
    QKV_STAGE(2, 64);

    const int ps = (quad ^ ((l16 >> 1) & 3)) * 8;      // swizzled read slot

#pragma unroll
    for (int kb = 0; kb < 12; ++kb) {
        // buffer kb complete when only the (newer) in-flight buffers remain
        if (kb <= 9)       asm volatile("s_waitcnt vmcnt(10)" ::: "memory");
        else if (kb == 10) asm volatile("s_waitcnt vmcnt(5)" ::: "memory");
        else               asm volatile("s_waitcnt vmcnt(0)" ::: "memory");
        __builtin_amdgcn_s_barrier();   // all waves done with step kb-1
        if (kb < 9) QKV_STAGE((kb + 3) & 3, (kb + 3) * 32);

        const int cur = kb & 3;
        bf16x8 a[4], b[6];
#pragma unroll
        for (int mi = 0; mi < 4; ++mi)
            a[mi] = *(const bf16x8*)&As[cur][mw + mi * 16 + l16][ps];
#pragma unroll
        for (int ni = 0; ni < 6; ++ni)
            b[ni] = *(const bf16x8*)&Bs[cur][nw + ni * 16 + l16][ps];
#pragma unroll
        for (int mi = 0; mi < 4; ++mi)
#pragma unroll
            for (int ni = 0; ni < 6; ++ni) acc[mi][ni] = mfma16(a[mi], b[ni], acc[mi][ni]);
    }
#undef QKV_STAGE

    // epilogue: per ni, tensor = (nw+ni*16)>>6 is wave-uniform
    const int b = m0 >> 8, tbase = m0 & 255;
    unsigned short* qkbase[2] = {
        Qo + (size_t)((b * Hn + h) * Tn) * Dn,
        Ko + (size_t)((b * Hn + h) * Tn) * Dn };
    unsigned short* vdst = Vt + (size_t)((b * Hn + h) * Dn) * Tn;
#pragma unroll
    for (int ni = 0; ni < 6; ++ni) {
        const int ng = nw + ni * 16;
        const int tensor = ng >> 6;
        const int d = (ng & 63) + l16;
        if (tensor < 2) {
            unsigned short* dst = qkbase[tensor];
#pragma unroll
            for (int mi = 0; mi < 4; ++mi)
#pragma unroll
                for (int r = 0; r < 4; ++r) {
                    int t = tbase + mw + mi * 16 + quad * 4 + r;
                    dst[t * Dn + d] = f2bf(acc[mi][ni][r]);
                }
        } else {
#pragma unroll
            for (int mi = 0; mi < 4; ++mi) {
                int t0 = tbase + mw + mi * 16 + quad * 4;
                ushort4 pk;
                pk.x = f2bf(acc[mi][ni][0]);
                pk.y = f2bf(acc[mi][ni][1]);
                pk.z = f2bf(acc[mi][ni][2]);
                pk.w = f2bf(acc[mi][ni][3]);
                *(ushort4*)&vdst[d * Tn + t0] = pk;
            }
        }
    }
}

// ---------------------------------------------------------------- attention (flash-style)
// grid (H, B): one block per (b,h). 4 waves, 256 threads.
// K[256][64] and V^T[64][256] staged in LDS once (XOR-swizzled), then
// barrier-free: wave w handles q-row-16-groups {w, 7-w, 8+w, 15-w}.
// Q frags for all 4 groups loaded BEFORE the barrier; setprio on MFMA.
__global__ __launch_bounds__(256) void attn_kernel(
    const unsigned short* __restrict__ Q, const unsigned short* __restrict__ K,
    const unsigned short* __restrict__ Vt, unsigned short* __restrict__ attout) {
    __shared__ unsigned short Kt[256][64];     // 32 KB, slot ^= (t&7)
    __shared__ unsigned short Vl[64][256];     // 32 KB, slot ^= (d&7)
    __shared__ unsigned short P[4][16][72];    // 9 KB, per-wave P / O staging

    const int h = blockIdx.x, b = blockIdx.y;
    const unsigned short* Qb = Q + (size_t)((b * Hn + h) * Tn) * Dn;
    const unsigned short* Kb = K + (size_t)((b * Hn + h) * Tn) * Dn;
    const unsigned short* Vb = Vt + (size_t)((b * Hn + h) * Dn) * Tn;

    const int tid = threadIdx.x;
    const int wave = tid >> 6, lane = tid & 63;
    const int quad = lane >> 4, l16 = lane & 15;

    const int grp[4] = {wave, 7 - wave, 8 + wave, 15 - wave};

    {
        const unsigned short* kg = Kb + (size_t)(lane >> 3) * Dn + ((lane & 7) ^ (lane >> 3)) * 8;
#pragma unroll
        for (int i = 0; i < 8; ++i) {
            const int c = wave * 8 + i;
            glds16(kg + (size_t)c * 8 * Dn, &Kt[c * 8][0]);
        }
#pragma unroll
        for (int i = 0; i < 8; ++i) {
            const int c = wave * 8 + i;
            const int d = c * 2 + (lane >> 5);
            const int j = (lane & 31) ^ (d & 7);
            glds16(Vb + (size_t)d * Tn + j * 8, &Vl[c * 2][0]);
        }
    }

    // hoist Q for all 4 groups: loads in flight under the staging DMA above
    bf16x8 aq[4][2];
#pragma unroll
    for (int gi = 0; gi < 4; ++gi) {
        const int q0 = grp[gi] * 16;
#pragma unroll
        for (int ks = 0; ks < 2; ++ks)
            aq[gi][ks] = *(const bf16x8*)&Qb[(q0 + l16) * Dn + ks * 32 + quad * 8];
    }

    __syncthreads();   // only barrier: K/V resident for the whole block

    const float cexp = 0.125f * 1.44269504f;   // scale * log2(e)

#pragma unroll
    for (int gi = 0; gi < 4; ++gi) {
        const int g = grp[gi];
        const int q0 = g * 16;

        f32x4 O[4];
#pragma unroll
        for (int i = 0; i < 4; ++i) O[i] = (f32x4){0.f, 0.f, 0.f, 0.f};
        float rsum[4] = {0.f, 0.f, 0.f, 0.f};

        const int ktmax = g >> 2;              // wave-uniform
        for (int kt = 0; kt <= ktmax; ++kt) {
            f32x4 S[4];
#pragma unroll
            for (int i = 0; i < 4; ++i) S[i] = (f32x4){0.f, 0.f, 0.f, 0.f};
            __builtin_amdgcn_s_setprio(1);
#pragma unroll
            for (int ks = 0; ks < 2; ++ks)
#pragma unroll
                for (int ni = 0; ni < 4; ++ni) {
                    bf16x8 bk = *(const bf16x8*)
                        &Kt[kt * 64 + ni * 16 + l16][(((ks * 4 + quad) ^ (l16 & 7)) * 8)];
                    S[ni] = mfma16(aq[gi][ks], bk, S[ni]);
                }
            __builtin_amdgcn_s_setprio(0);

#pragma unroll
            for (int ni = 0; ni < 4; ++ni)
#pragma unroll
                for (int r = 0; r < 4; ++r) {
                    int col = kt * 64 + ni * 16 + l16;
                    float p = exp2f(S[ni][r] * cexp);
                    p = (col > q0 + quad * 4 + r) ? 0.f : p;
                    rsum[r] += p;
                    P[wave][quad * 4 + r][ni * 16 + l16] = f2bf(p);
                }

            __builtin_amdgcn_s_setprio(1);
#pragma unroll
            for (int ks = 0; ks < 2; ++ks) {
                bf16x8 ap = *(const bf16x8*)&P[wave][l16][ks * 32 + quad * 8];
#pragma unroll
                for (int ni = 0; ni < 4; ++ni) {
                    bf16x8 bv = *(const bf16x8*)
                        &Vl[ni * 16 + l16][(((kt * 8 + ks * 4 + quad) ^ (l16 & 7)) * 8)];
                    O[ni] = mfma16(ap, bv, O[ni]);
                }
            }
            __builtin_amdgcn_s_setprio(0);
        }

#pragma unroll
        for (int r = 0; r < 4; ++r) {
            float s = rsum[r];
            s += __shfl_xor(s, 1);
            s += __shfl_xor(s, 2);
            s += __shfl_xor(s, 4);
            s += __shfl_xor(s, 8);
            rsum[r] = s;
        }

#pragma unroll
        for (int r = 0; r < 4; ++r) {
            float inv = 1.0f / rsum[r];
#pragma unroll
            for (int ni = 0; ni < 4; ++ni)
                P[wave][quad * 4 + r][ni * 16 + l16] = f2bf(O[ni][r] * inv);
        }
        const int row = lane >> 2;             // 0..15
        const int colc = (lane & 3) * 16;      // 0,16,32,48
        unsigned short* dst = attout + (size_t)(b * Tn + q0 + row) * (Hn * Dn) + h * Dn + colc;
        *(uint4*)dst = *(const uint4*)&P[wave][row][colc];
        *(uint4*)(dst + 8) = *(const uint4*)&P[wave][row][colc + 8];
    }
}

// ---------------------------------------------------------------- output projection
// grid 1536 (flattened, XCD swizzle; n fast). 128x128 tile, double-buffered,
// counted vmcnt (per-wave loads/tile = 8).
__global__ __launch_bounds__(256) void proj_gemm(
    const unsigned short* __restrict__ attout, const unsigned short* __restrict__ wpt,
    const float* __restrict__ bproj, float* __restrict__ out) {
    __shared__ unsigned short As[2][128][64];   // 32 KB
    __shared__ unsigned short Bs[2][128][64];   // 32 KB (64 KB total, 2 blk/CU)

    const int bid = blockIdx.x;
    const int swz = (bid & 7) * 192 + (bid >> 3);   // 1536/8 = 192, bijective
    const int n0 = (swz % 3) * 128;
    const int m0 = (swz / 3) * 128;

    const int tid = threadIdx.x;
    const int wave = tid >> 6, lane = tid & 63;
    const int quad = lane >> 4, l16 = lane & 15;
    const int mw = (wave >> 1) * 64, nw = (wave & 1) * 64;

    f32x4 acc[4][4];
#pragma unroll
    for (int i = 0; i < 4; ++i)
#pragma unroll
        for (int j = 0; j < 4; ++j) acc[i][j] = (f32x4){0.f, 0.f, 0.f, 0.f};

    const int lr = lane >> 3;
    const int js = (lane & 7) ^ lr;

    const unsigned short* ga[4];
    const unsigned short* gb[4];
#pragma unroll
    for (int i = 0; i < 4; ++i) {
        ga[i] = attout + (size_t)(m0 + wave * 32 + i * 8 + lr) * En + js * 8;
        gb[i] = wpt + (size_t)(n0 + wave * 32 + i * 8 + lr) * En + js * 8;
    }

#define PROJ_STAGE(buf, koff)                                             \
    do {                                                                  \
        _Pragma("unroll") for (int i = 0; i < 4; ++i)                     \
            glds16(ga[i] + (koff), &As[buf][wave * 32 + i * 8][0]);       \
        _Pragma("unroll") for (int i = 0; i < 4; ++i)                     \
            glds16(gb[i] + (koff), &Bs[buf][wave * 32 + i * 8][0]);       \
    } while (0)

    PROJ_STAGE(0, 0);
    PROJ_STAGE(1, 64);

#pragma unroll
    for (int kb = 0; kb < 6; ++kb) {
        if (kb < 5) asm volatile("s_waitcnt vmcnt(8)" ::: "memory");
        else        asm volatile("s_waitcnt vmcnt(0)" ::: "memory");
        __builtin_amdgcn_s_barrier();

        const int cur = kb & 1;
        __builtin_amdgcn_s_setprio(1);
#pragma unroll
        for (int ks = 0; ks < 2; ++ks) {
            bf16x8 a[4], bb[4];
            const int ps = ((ks * 4 + quad) ^ (l16 & 7)) * 8;
#pragma unroll
            for (int mi = 0; mi < 4; ++mi)
                a[mi] = *(const bf16x8*)&As[cur][mw + mi * 16 + l16][ps];
#pragma unroll
            for (int ni = 0; ni < 4; ++ni)
                bb[ni] = *(const bf16x8*)&Bs[cur][nw + ni * 16 + l16][ps];
#pragma unroll
            for (int mi = 0; mi < 4; ++mi)
#pragma unroll
                for (int ni = 0; ni < 4; ++ni) acc[mi][ni] = mfma16(a[mi], bb[ni], acc[mi][ni]);
        }
        __builtin_amdgcn_s_setprio(0);

        if (kb < 4) {
            __builtin_amdgcn_s_barrier();
            PROJ_STAGE(cur, (kb + 2) * 64);
        }
    }
#undef PROJ_STAGE

#pragma unroll
    for (int mi = 0; mi < 4; ++mi)
#pragma unroll
        for (int ni = 0; ni < 4; ++ni)
#pragma unroll
            for (int r = 0; r < 4; ++r) {
                int row = m0 + mw + mi * 16 + quad * 4 + r;
                int col = n0 + nw + ni * 16 + l16;
                out[(size_t)row * En + col] = acc[mi][ni][r] + bproj[col];
            }
}

// ---------------------------------------------------------------- launch
extern "C" void kernel_launch(void* const* d_in, const int* in_sizes, int n_in,
                              void* d_out, int out_size, void* d_ws, size_t ws_size,
                              hipStream_t stream) {
    const float* x  = (const float*)d_in[0];
    const float* wq = (const float*)d_in[1];
    const float* wk = (const float*)d_in[2];
    const float* wv = (const float*)d_in[3];
    const float* wp = (const float*)d_in[4];
    const float* bp = (const float*)d_in[5];
    float* out = (float*)d_out;

    char* ws = (char*)d_ws;
    const size_t WT_OFF  = 0;                                  // 884736
    const size_t WPT_OFF = WT_OFF + 884736;                    // 294912
    const size_t Q_OFF   = WPT_OFF + 294912;                   // 50331648 each below
    const size_t K_OFF   = Q_OFF + 50331648ull;
    const size_t VT_OFF  = K_OFF + 50331648ull;
    const size_t XB_OFF  = VT_OFF + 50331648ull;               // xb; attout aliases this

    unsigned short* wt   = (unsigned short*)(ws + WT_OFF);
    unsigned short* wpt  = (unsigned short*)(ws + WPT_OFF);
    unsigned short* Qd   = (unsigned short*)(ws + Q_OFF);
    unsigned short* Kd   = (unsigned short*)(ws + K_OFF);
    unsigned short* Vtd  = (unsigned short*)(ws + VT_OFF);
    unsigned short* xbd  = (unsigned short*)(ws + XB_OFF);
    unsigned short* ao   = xbd;   // xb dead after qkv_gemm; attn overwrites it

    prep_xcast_kernel<<<14592, 256, 0, stream>>>(wq, wk, wv, wp, x, wt, wpt, xbd);
    qkv_gemm<<<3072, 256, 0, stream>>>(xbd, wt, Qd, Kd, Vtd);
    attn_kernel<<<dim3(Hn, Bn), 256, 0, stream>>>(Qd, Kd, Vtd, ao);
    proj_gemm<<<1536, 256, 0, stream>>>(ao, wpt, bp, out);
}

// Round 9
// 354.899 us; speedup vs baseline: 1.0156x; 1.0156x over previous
//
#include <hip/hip_runtime.h>
#include <hip/hip_bf16.h>

// MHA: B=256, T=256, E=384, H=6, D=64.  fp32 in/out, bf16 MFMA internally.
//
//   prep+xcast: fused: blocks [0,12288) cast x->bf16, rest repack weights.
//   qkvattn (ROUND 9, FUSED): one block per (b,h). Phase 1: GEMM
//          256x192x384 (two 128-row halves, BK=32 triple-buffered staging,
//          single s_barrier + counted vmcnt per step), epilogue writes
//          Q/K/V straight into swizzled LDS (byte-identical layout to the
//          old glds16-staged Kt/Vl, so the attn phase is unchanged).
//          Phase 2: round-4/7 attn body (barrier-free causal groups
//          {w,7-w,8+w,15-w}) reading Kt/Vl/Qs from LDS.
//          Deletes 300 MB of HBM roundtrip + one launch + device drain.
//          LDS 156 KB -> 1 blk/CU (P aliases dead GEMM staging).
//   proj:  round-7 form (BK=64 dbuf counted vmcnt + setprio), attout now in
//          its own ws region (it used to alias xb; fused kernel reads xb and
//          writes attout concurrently across blocks, so no aliasing allowed).

#define Bn 256
#define Tn 256
#define En 384
#define Hn 6
#define Dn 64

typedef __bf16 bf16x8 __attribute__((ext_vector_type(8)));
typedef float f32x4 __attribute__((ext_vector_type(4)));
typedef unsigned short u16x8 __attribute__((ext_vector_type(8)));

static __device__ __forceinline__ unsigned short f2bf(float f) {
    unsigned int u = __builtin_bit_cast(unsigned int, f);
    u += 0x7fffu + ((u >> 16) & 1u);   // RNE
    return (unsigned short)(u >> 16);
}

static __device__ __forceinline__ f32x4 mfma16(bf16x8 a, bf16x8 b, f32x4 c) {
    return __builtin_amdgcn_mfma_f32_16x16x32_bf16(a, b, c, 0, 0, 0);
}

// async global->LDS, 16 B per lane. LDS dest = wave-uniform base + lane*16.
static __device__ __forceinline__ void glds16(const unsigned short* g, unsigned short* l) {
    __builtin_amdgcn_global_load_lds(
        (const __attribute__((address_space(1))) unsigned int*)g,
        (__attribute__((address_space(3))) unsigned int*)l, 16, 0, 0);
}

// ---------------------------------------------------------------- prep + xcast (fused)
__global__ __launch_bounds__(256) void prep_xcast_kernel(
    const float* __restrict__ wq, const float* __restrict__ wk,
    const float* __restrict__ wv, const float* __restrict__ wp,
    const float* __restrict__ x,
    unsigned short* __restrict__ wt, unsigned short* __restrict__ wpt,
    unsigned short* __restrict__ xb) {
    const int bid = blockIdx.x;
    if (bid < 12288) {
        size_t i = ((size_t)bid * 256 + threadIdx.x) * 8;
        float4 f0 = *(const float4*)(x + i);
        float4 f1 = *(const float4*)(x + i + 4);
        u16x8 p;
        p[0] = f2bf(f0.x); p[1] = f2bf(f0.y); p[2] = f2bf(f0.z); p[3] = f2bf(f0.w);
        p[4] = f2bf(f1.x); p[5] = f2bf(f1.y); p[6] = f2bf(f1.z); p[7] = f2bf(f1.w);
        *(u16x8*)(xb + i) = p;
    } else {
        const int NW = 3 * Hn * Dn * En;      // 442368
        const int NP = En * En;               // 147456
        int idx = (bid - 12288) * 256 + threadIdx.x;
        if (idx < NW) {
            int e = idx % En;
            int d = (idx / En) % Dn;
            int h = (idx / (En * Dn)) % Hn;
            int t = idx / (En * Dn * Hn);
            const float* src = (t == 0) ? wq : (t == 1) ? wk : wv;
            wt[idx] = f2bf(src[(h * En + e) * Dn + d]);
        } else if (idx < NW + NP) {
            int j = idx - NW;
            int k = j % En;
            int n = j / En;
            wpt[j] = f2bf(wp[k * En + n]);
        }
    }
}

// ---------------------------------------------------------------- fused QKV + attention
// grid 1536: (b,h) with XCD swizzle (consecutive swz share b -> x L2 reuse).
// LDS map (u16 offsets):
//   Kt[256][64]   @ 0       (32 KB)  K, slot ^= (t&7)  - same layout attn always used
//   Vl[64][256]   @ 16384   (32 KB)  V^T, slot ^= (d&7)
//   Qs[256][64]   @ 32768   (32 KB)  Q, slot ^= (t&7)
//   As[3][128][32]@ 49152   (24 KB)  GEMM A staging (BK=32 triple buffer)
//   Bs[3][192][32]@ 61440   (36 KB)  GEMM B staging
//   P[4][16][72]  aliases As (attn phase only; staging dead by then)
// GEMM: per half (128 rows), 12 BK=32 steps; per step: s_barrier ->
// STAGE(k+2) -> vmcnt(10) -> 24 MFMA/wave. Per-wave loads/buffer = 5.
__global__ __launch_bounds__(256, 1) void qkvattn_kernel(
    const unsigned short* __restrict__ xb, const unsigned short* __restrict__ wt,
    unsigned short* __restrict__ attout) {
    __shared__ __align__(16) unsigned short smem[79872];   // 156 KB
    unsigned short (*Kt)[64]      = (unsigned short(*)[64])(smem);
    unsigned short (*Vl)[256]     = (unsigned short(*)[256])(smem + 16384);
    unsigned short (*Qs)[64]      = (unsigned short(*)[64])(smem + 32768);
    unsigned short (*As)[128][32] = (unsigned short(*)[128][32])(smem + 49152);
    unsigned short (*Bs)[192][32] = (unsigned short(*)[192][32])(smem + 61440);
    unsigned short (*P)[16][72]   = (unsigned short(*)[16][72])(smem + 49152); // alias

    const int bid = blockIdx.x;
    const int swz = (bid & 7) * 192 + (bid >> 3);   // 1536/8 = 192, bijective
    const int bi = swz / Hn;
    const int h  = swz % Hn;

    const int tid = threadIdx.x;
    const int wave = tid >> 6, lane = tid & 63;
    const int quad = lane >> 4, l16 = lane & 15;
    const int mw = (wave >> 1) * 64, nw = (wave & 1) * 96;

    f32x4 acc[4][6];
#pragma unroll
    for (int i = 0; i < 4; ++i)
#pragma unroll
        for (int j = 0; j < 6; ++j) acc[i][j] = (f32x4){0.f, 0.f, 0.f, 0.f};

    // BK=32 staging geometry (round-8 verified): chunk = 16 rows x 32 cols.
    // lane l -> row l>>2, phys 8-elem slot l&3; source slot (l&3)^((l>>3)&3).
    const int lrow = lane >> 2;
    const int js = (lane & 3) ^ ((lane >> 3) & 3);

    const unsigned short* ga[2];
#pragma unroll
    for (int i = 0; i < 2; ++i)
        ga[i] = xb + (size_t)(bi * 256 + wave * 32 + i * 16 + lrow) * En + js * 8;
    const unsigned short* gb[3];
#pragma unroll
    for (int i = 0; i < 3; ++i) {
        int n = wave * 48 + i * 16 + lrow;
        gb[i] = wt + (size_t)(((n >> 6) * Hn + h) * Dn + (n & 63)) * En + js * 8;
    }

    // chunk c in [0,24): half = c/12, koff = (c%12)*32
#define QA_STAGE(c)                                                          \
    do {                                                                     \
        const int _buf = (c) % 3;                                            \
        const size_t _ao = (size_t)((c) / 12) * (128 * En) + ((c) % 12) * 32;\
        const size_t _bo = (size_t)((c) % 12) * 32;                          \
        glds16(ga[0] + _ao, &As[_buf][wave * 32][0]);                        \
        glds16(ga[1] + _ao, &As[_buf][wave * 32 + 16][0]);                   \
        glds16(gb[0] + _bo, &Bs[_buf][wave * 48][0]);                        \
        glds16(gb[1] + _bo, &Bs[_buf][wave * 48 + 16][0]);                   \
        glds16(gb[2] + _bo, &Bs[_buf][wave * 48 + 32][0]);                   \
    } while (0)

    // epilogue: write this half's Q/K/V fragments into swizzled LDS.
    // tensor = (nw+ni*16)>>6 wave-uniform; layouts match the attn reads:
    //   Qs/Kt[t][ ((d>>3)^(t&7))*8 + (d&7) ],  Vl[d][ ((t>>3)^(d&7))*8 + (t&7) ]
#define QA_EPI(half)                                                         \
    do {                                                                     \
        _Pragma("unroll") for (int ni = 0; ni < 6; ++ni) {                   \
            const int ng = nw + ni * 16;                                     \
            const int tensor = ng >> 6;                                      \
            const int d = (ng & 63) + l16;                                   \
            if (tensor == 2) {                                               \
                _Pragma("unroll") for (int mi = 0; mi < 4; ++mi) {           \
                    const int t0 = (half) * 128 + mw + mi * 16 + quad * 4;   \
                    ushort4 pk;                                              \
                    pk.x = f2bf(acc[mi][ni][0]);                             \
                    pk.y = f2bf(acc[mi][ni][1]);                             \
                    pk.z = f2bf(acc[mi][ni][2]);                             \
                    pk.w = f2bf(acc[mi][ni][3]);                             \
                    *(ushort4*)&Vl[d][((((t0 >> 3) ^ (d & 7))) << 3) + (t0 & 4)] = pk; \
                }                                                            \
            } else {                                                         \
                unsigned short(*dstl)[64] = (tensor == 0) ? Qs : Kt;         \
                _Pragma("unroll") for (int mi = 0; mi < 4; ++mi)             \
                    _Pragma("unroll") for (int r = 0; r < 4; ++r) {          \
                        const int t = (half) * 128 + mw + mi * 16 + quad * 4 + r; \
                        dstl[t][((((d >> 3) ^ (t & 7))) << 3) + (d & 7)] =   \
                            f2bf(acc[mi][ni][r]);                            \
                    }                                                        \
            }                                                                \
        }                                                                    \
    } while (0)

    QA_STAGE(0);
    QA_STAGE(1);

    const int ps = (quad ^ ((l16 >> 1) & 3)) * 8;      // swizzled read slot

#pragma unroll
    for (int k = 0; k < 24; ++k) {
        __builtin_amdgcn_s_barrier();        // all waves done with step k-1
        if (k < 22) {
            QA_STAGE(k + 2);                 // issue before the wait: overlaps
            asm volatile("s_waitcnt vmcnt(10)" ::: "memory");   // chunk k done
        } else if (k == 22) {
            asm volatile("s_waitcnt vmcnt(5)" ::: "memory");
        } else {
            asm volatile("s_waitcnt vmcnt(0)" ::: "memory");
        }

        const int cur = k % 3;
        bf16x8 a[4], bq[6];
#pragma unroll
        for (int mi = 0; mi < 4; ++mi)
            a[mi] = *(const bf16x8*)&As[cur][mw + mi * 16 + l16][ps];
#pragma unroll
        for (int ni = 0; ni < 6; ++ni)
            bq[ni] = *(const bf16x8*)&Bs[cur][nw + ni * 16 + l16][ps];
#pragma unroll
        for (int mi = 0; mi < 4; ++mi)
#pragma unroll
            for (int ni = 0; ni < 6; ++ni) acc[mi][ni] = mfma16(a[mi], bq[ni], acc[mi][ni]);

        if (k == 11) {
            QA_EPI(0);                       // half-0 Q/K/V -> LDS (disjoint regions)
#pragma unroll
            for (int i = 0; i < 4; ++i)
#pragma unroll
                for (int j = 0; j < 6; ++j) acc[i][j] = (f32x4){0.f, 0.f, 0.f, 0.f};
        }
    }
    QA_EPI(1);
#undef QA_STAGE
#undef QA_EPI

    __syncthreads();   // Q/K/V resident in LDS; staging dead -> P alias valid

    // ---- attention phase (round-4/7 body, Q from LDS) ----
    const float cexp = 0.125f * 1.44269504f;   // scale * log2(e)
    const int grp[4] = {wave, 7 - wave, 8 + wave, 15 - wave};

#pragma unroll
    for (int gi = 0; gi < 4; ++gi) {
        const int g = grp[gi];
        const int q0 = g * 16;

        bf16x8 aq[2];
#pragma unroll
        for (int ks = 0; ks < 2; ++ks)
            aq[ks] = *(const bf16x8*)&Qs[q0 + l16][(((ks * 4 + quad) ^ (l16 & 7)) * 8)];

        f32x4 O[4];
#pragma unroll
        for (int i = 0; i < 4; ++i) O[i] = (f32x4){0.f, 0.f, 0.f, 0.f};
        float rsum[4] = {0.f, 0.f, 0.f, 0.f};

        const int ktmax = g >> 2;              // wave-uniform
        for (int kt = 0; kt <= ktmax; ++kt) {
            f32x4 S[4];
#pragma unroll
            for (int i = 0; i < 4; ++i) S[i] = (f32x4){0.f, 0.f, 0.f, 0.f};
            __builtin_amdgcn_s_setprio(1);
#pragma unroll
            for (int ks = 0; ks < 2; ++ks)
#pragma unroll
                for (int ni = 0; ni < 4; ++ni) {
                    bf16x8 bk = *(const bf16x8*)
                        &Kt[kt * 64 + ni * 16 + l16][(((ks * 4 + quad) ^ (l16 & 7)) * 8)];
                    S[ni] = mfma16(aq[ks], bk, S[ni]);
                }
            __builtin_amdgcn_s_setprio(0);

#pragma unroll
            for (int ni = 0; ni < 4; ++ni)
#pragma unroll
                for (int r = 0; r < 4; ++r) {
                    int col = kt * 64 + ni * 16 + l16;
                    float p = exp2f(S[ni][r] * cexp);
                    p = (col > q0 + quad * 4 + r) ? 0.f : p;
                    rsum[r] += p;
                    P[wave][quad * 4 + r][ni * 16 + l16] = f2bf(p);
                }

            __builtin_amdgcn_s_setprio(1);
#pragma unroll
            for (int ks = 0; ks < 2; ++ks) {
                bf16x8 ap = *(const bf16x8*)&P[wave][l16][ks * 32 + quad * 8];
#pragma unroll
                for (int ni = 0; ni < 4; ++ni) {
                    bf16x8 bv = *(const bf16x8*)
                        &Vl[ni * 16 + l16][(((kt * 8 + ks * 4 + quad) ^ (l16 & 7)) * 8)];
                    O[ni] = mfma16(ap, bv, O[ni]);
                }
            }
            __builtin_amdgcn_s_setprio(0);
        }

#pragma unroll
        for (int r = 0; r < 4; ++r) {
            float s = rsum[r];
            s += __shfl_xor(s, 1);
            s += __shfl_xor(s, 2);
            s += __shfl_xor(s, 4);
            s += __shfl_xor(s, 8);
            rsum[r] = s;
        }

#pragma unroll
        for (int r = 0; r < 4; ++r) {
            float inv = 1.0f / rsum[r];
#pragma unroll
            for (int ni = 0; ni < 4; ++ni)
                P[wave][quad * 4 + r][ni * 16 + l16] = f2bf(O[ni][r] * inv);
        }
        const int row = lane >> 2;             // 0..15
        const int colc = (lane & 3) * 16;      // 0,16,32,48
        unsigned short* dst = attout + (size_t)(bi * Tn + q0 + row) * (Hn * Dn) + h * Dn + colc;
        *(uint4*)dst = *(const uint4*)&P[wave][row][colc];
        *(uint4*)(dst + 8) = *(const uint4*)&P[wave][row][colc + 8];
    }
}

// ---------------------------------------------------------------- output projection
// grid 1536 (flattened, XCD swizzle; n fast). 128x128 tile, double-buffered,
// counted vmcnt (per-wave loads/tile = 8).
__global__ __launch_bounds__(256) void proj_gemm(
    const unsigned short* __restrict__ attout, const unsigned short* __restrict__ wpt,
    const float* __restrict__ bproj, float* __restrict__ out) {
    __shared__ unsigned short As[2][128][64];   // 32 KB
    __shared__ unsigned short Bs[2][128][64];   // 32 KB (64 KB total, 2 blk/CU)

    const int bid = blockIdx.x;
    const int swz = (bid & 7) * 192 + (bid >> 3);   // 1536/8 = 192, bijective
    const int n0 = (swz % 3) * 128;
    const int m0 = (swz / 3) * 128;

    const int tid = threadIdx.x;
    const int wave = tid >> 6, lane = tid & 63;
    const int quad = lane >> 4, l16 = lane & 15;
    const int mw = (wave >> 1) * 64, nw = (wave & 1) * 64;

    f32x4 acc[4][4];
#pragma unroll
    for (int i = 0; i < 4; ++i)
#pragma unroll
        for (int j = 0; j < 4; ++j) acc[i][j] = (f32x4){0.f, 0.f, 0.f, 0.f};

    const int lr = lane >> 3;
    const int js = (lane & 7) ^ lr;

    const unsigned short* ga[4];
    const unsigned short* gb[4];
#pragma unroll
    for (int i = 0; i < 4; ++i) {
        ga[i] = attout + (size_t)(m0 + wave * 32 + i * 8 + lr) * En + js * 8;
        gb[i] = wpt + (size_t)(n0 + wave * 32 + i * 8 + lr) * En + js * 8;
    }

#define PROJ_STAGE(buf, koff)                                             \
    do {                                                                  \
        _Pragma("unroll") for (int i = 0; i < 4; ++i)                     \
            glds16(ga[i] + (koff), &As[buf][wave * 32 + i * 8][0]);       \
        _Pragma("unroll") for (int i = 0; i < 4; ++i)                     \
            glds16(gb[i] + (koff), &Bs[buf][wave * 32 + i * 8][0]);       \
    } while (0)

    PROJ_STAGE(0, 0);
    PROJ_STAGE(1, 64);

#pragma unroll
    for (int kb = 0; kb < 6; ++kb) {
        if (kb < 5) asm volatile("s_waitcnt vmcnt(8)" ::: "memory");
        else        asm volatile("s_waitcnt vmcnt(0)" ::: "memory");
        __builtin_amdgcn_s_barrier();

        const int cur = kb & 1;
        __builtin_amdgcn_s_setprio(1);
#pragma unroll
        for (int ks = 0; ks < 2; ++ks) {
            bf16x8 a[4], bb[4];
            const int ps = ((ks * 4 + quad) ^ (l16 & 7)) * 8;
#pragma unroll
            for (int mi = 0; mi < 4; ++mi)
                a[mi] = *(const bf16x8*)&As[cur][mw + mi * 16 + l16][ps];
#pragma unroll
            for (int ni = 0; ni < 4; ++ni)
                bb[ni] = *(const bf16x8*)&Bs[cur][nw + ni * 16 + l16][ps];
#pragma unroll
            for (int mi = 0; mi < 4; ++mi)
#pragma unroll
                for (int ni = 0; ni < 4; ++ni) acc[mi][ni] = mfma16(a[mi], bb[ni], acc[mi][ni]);
        }
        __builtin_amdgcn_s_setprio(0);

        if (kb < 4) {
            __builtin_amdgcn_s_barrier();
            PROJ_STAGE(cur, (kb + 2) * 64);
        }
    }
#undef PROJ_STAGE

#pragma unroll
    for (int mi = 0; mi < 4; ++mi)
#pragma unroll
        for (int ni = 0; ni < 4; ++ni)
#pragma unroll
            for (int r = 0; r < 4; ++r) {
                int row = m0 + mw + mi * 16 + quad * 4 + r;
                int col = n0 + nw + ni * 16 + l16;
                out[(size_t)row * En + col] = acc[mi][ni][r] + bproj[col];
            }
}

// ---------------------------------------------------------------- launch
extern "C" void kernel_launch(void* const* d_in, const int* in_sizes, int n_in,
                              void* d_out, int out_size, void* d_ws, size_t ws_size,
                              hipStream_t stream) {
    const float* x  = (const float*)d_in[0];
    const float* wq = (const float*)d_in[1];
    const float* wk = (const float*)d_in[2];
    const float* wv = (const float*)d_in[3];
    const float* wp = (const float*)d_in[4];
    const float* bp = (const float*)d_in[5];
    float* out = (float*)d_out;

    char* ws = (char*)d_ws;
    const size_t WT_OFF  = 0;                                  // 884736
    const size_t WPT_OFF = WT_OFF + 884736;                    // 294912
    const size_t AO_OFF  = WPT_OFF + 294912;                   // attout: 50331648
    const size_t XB_OFF  = AO_OFF + 50331648ull;               // xb (distinct from attout!)

    unsigned short* wt   = (unsigned short*)(ws + WT_OFF);
    unsigned short* wpt  = (unsigned short*)(ws + WPT_OFF);
    unsigned short* ao   = (unsigned short*)(ws + AO_OFF);
    unsigned short* xbd  = (unsigned short*)(ws + XB_OFF);

    prep_xcast_kernel<<<14592, 256, 0, stream>>>(wq, wk, wv, wp, x, wt, wpt, xbd);
    qkvattn_kernel<<<1536, 256, 0, stream>>>(xbd, wt, ao);
    proj_gemm<<<1536, 256, 0, stream>>>(ao, wpt, bp, out);
}

// Round 10
// 348.303 us; speedup vs baseline: 1.0348x; 1.0189x over previous
//
#include <hip/hip_runtime.h>
#include <hip/hip_bf16.h>

// MHA: B=256, T=256, E=384, H=6, D=64.  fp32 in/out, bf16 MFMA internally.
//
//   prep+xcast: fused: blocks [0,12288) cast x->bf16, rest repack weights.
//   qkv:   round-6 form (best measured: 77 us): BK=64 double-buffered LDS,
//          counted vmcnt(10), raw s_barrier pair per step, glds16 staging,
//          T21 both-sides XOR swizzle (0 conflicts), bijective XCD swizzle.
//          NO setprio (round-7 A/B: -6 us on this structure).
//   attn:  round-7 form: one block per (b,h); K/V staged in LDS once;
//          barrier-free causal groups {w,7-w,8+w,15-w}; Q hoisted pre-barrier;
//          setprio on MFMA clusters (T5 positive on attn).
//   proj:  round-6 form (setprio removed - same structure as qkv, same
//          predicted penalty).
//
//   Round-9 lesson: qkv+attn fusion (1 blk/CU, 24-step BK=32 pipeline,
//   LDS epilogue) = 164 us vs ~140 separate despite 300 MB traffic saved -
//   barrier/latency-bound regime, traffic irrelevant.

#define Bn 256
#define Tn 256
#define En 384
#define Hn 6
#define Dn 64

typedef __bf16 bf16x8 __attribute__((ext_vector_type(8)));
typedef float f32x4 __attribute__((ext_vector_type(4)));
typedef unsigned short u16x8 __attribute__((ext_vector_type(8)));

static __device__ __forceinline__ unsigned short f2bf(float f) {
    unsigned int u = __builtin_bit_cast(unsigned int, f);
    u += 0x7fffu + ((u >> 16) & 1u);   // RNE
    return (unsigned short)(u >> 16);
}

static __device__ __forceinline__ f32x4 mfma16(bf16x8 a, bf16x8 b, f32x4 c) {
    return __builtin_amdgcn_mfma_f32_16x16x32_bf16(a, b, c, 0, 0, 0);
}

// async global->LDS, 16 B per lane. LDS dest = wave-uniform base + lane*16.
static __device__ __forceinline__ void glds16(const unsigned short* g, unsigned short* l) {
    __builtin_amdgcn_global_load_lds(
        (const __attribute__((address_space(1))) unsigned int*)g,
        (__attribute__((address_space(3))) unsigned int*)l, 16, 0, 0);
}

// ---------------------------------------------------------------- prep + xcast (fused)
__global__ __launch_bounds__(256) void prep_xcast_kernel(
    const float* __restrict__ wq, const float* __restrict__ wk,
    const float* __restrict__ wv, const float* __restrict__ wp,
    const float* __restrict__ x,
    unsigned short* __restrict__ wt, unsigned short* __restrict__ wpt,
    unsigned short* __restrict__ xb) {
    const int bid = blockIdx.x;
    if (bid < 12288) {
        size_t i = ((size_t)bid * 256 + threadIdx.x) * 8;
        float4 f0 = *(const float4*)(x + i);
        float4 f1 = *(const float4*)(x + i + 4);
        u16x8 p;
        p[0] = f2bf(f0.x); p[1] = f2bf(f0.y); p[2] = f2bf(f0.z); p[3] = f2bf(f0.w);
        p[4] = f2bf(f1.x); p[5] = f2bf(f1.y); p[6] = f2bf(f1.z); p[7] = f2bf(f1.w);
        *(u16x8*)(xb + i) = p;
    } else {
        const int NW = 3 * Hn * Dn * En;      // 442368
        const int NP = En * En;               // 147456
        int idx = (bid - 12288) * 256 + threadIdx.x;
        if (idx < NW) {
            int e = idx % En;
            int d = (idx / En) % Dn;
            int h = (idx / (En * Dn)) % Hn;
            int t = idx / (En * Dn * Hn);
            const float* src = (t == 0) ? wq : (t == 1) ? wk : wv;
            wt[idx] = f2bf(src[(h * En + e) * Dn + d]);
        } else if (idx < NW + NP) {
            int j = idx - NW;
            int k = j % En;
            int n = j / En;
            wpt[j] = f2bf(wp[k * En + n]);
        }
    }
}

// ---------------------------------------------------------------- QKV projection (merged)
// grid 3072 (flattened): bijective XCD swizzle; logical order = head-fast.
// Tile 128x192, 4 waves 2x2, wave 64x96 (acc[4][6]).
// Double-buffered LDS, counted vmcnt (per-wave loads/tile = 4 A + 6 B = 10).
__global__ __launch_bounds__(256) void qkv_gemm(
    const unsigned short* __restrict__ xb, const unsigned short* __restrict__ wt,
    unsigned short* __restrict__ Qo, unsigned short* __restrict__ Ko,
    unsigned short* __restrict__ Vt) {
    __shared__ unsigned short As[2][128][64];   // 32 KB
    __shared__ unsigned short Bs[2][192][64];   // 48 KB  (80 KB total, 2 blk/CU)

    const int bid = blockIdx.x;
    const int swz = (bid & 7) * 384 + (bid >> 3);   // 3072/8 = 384, bijective
    const int h = swz % Hn;
    const int m0 = (swz / Hn) * 128;

    const int tid = threadIdx.x;
    const int wave = tid >> 6, lane = tid & 63;
    const int quad = lane >> 4, l16 = lane & 15;
    const int mw = (wave >> 1) * 64, nw = (wave & 1) * 96;

    f32x4 acc[4][6];
#pragma unroll
    for (int i = 0; i < 4; ++i)
#pragma unroll
        for (int j = 0; j < 6; ++j) acc[i][j] = (f32x4){0.f, 0.f, 0.f, 0.f};

    // staging geometry: chunk = 8 rows x 64 cols (1 KB = 64 lanes x 16 B).
    // lane l -> row 8k + (l>>3), physical 16B-slot l&7.
    // pre-swizzled source: logical slot j = (l&7) ^ (l>>3)  (row&7 == l>>3).
    const int lr = lane >> 3;
    const int js = (lane & 7) ^ lr;

    const unsigned short* ga[4];
#pragma unroll
    for (int i = 0; i < 4; ++i)
        ga[i] = xb + (size_t)(m0 + wave * 32 + i * 8 + lr) * En + js * 8;
    const unsigned short* gb[6];
#pragma unroll
    for (int i = 0; i < 6; ++i) {
        int n = wave * 48 + i * 8 + lr;
        gb[i] = wt + (size_t)(((n >> 6) * Hn + h) * Dn + (n & 63)) * En + js * 8;
    }

#define QKV_STAGE(buf, koff)                                              \
    do {                                                                  \
        _Pragma("unroll") for (int i = 0; i < 4; ++i)                     \
            glds16(ga[i] + (koff), &As[buf][wave * 32 + i * 8][0]);       \
        _Pragma("unroll") for (int i = 0; i < 6; ++i)                     \
            glds16(gb[i] + (koff), &Bs[buf][wave * 48 + i * 8][0]);       \
    } while (0)

    QKV_STAGE(0, 0);
    QKV_STAGE(1, 64);

#pragma unroll
    for (int kb = 0; kb < 6; ++kb) {
        // wait for tile kb's own 10 loads only (tile kb+1's stay in flight)
        if (kb < 5) asm volatile("s_waitcnt vmcnt(10)" ::: "memory");
        else        asm volatile("s_waitcnt vmcnt(0)" ::: "memory");
        __builtin_amdgcn_s_barrier();   // raw: no vmcnt(0) drain

        const int cur = kb & 1;
#pragma unroll
        for (int ks = 0; ks < 2; ++ks) {
            bf16x8 a[4], b[6];
            const int ps = ((ks * 4 + quad) ^ (l16 & 7)) * 8;  // swizzled slot
#pragma unroll
            for (int mi = 0; mi < 4; ++mi)
                a[mi] = *(const bf16x8*)&As[cur][mw + mi * 16 + l16][ps];
#pragma unroll
            for (int ni = 0; ni < 6; ++ni)
                b[ni] = *(const bf16x8*)&Bs[cur][nw + ni * 16 + l16][ps];
#pragma unroll
            for (int mi = 0; mi < 4; ++mi)
#pragma unroll
                for (int ni = 0; ni < 6; ++ni) acc[mi][ni] = mfma16(a[mi], b[ni], acc[mi][ni]);
        }

        if (kb < 4) {
            // all waves done reading buf[cur] before its DMA overwrite
            __builtin_amdgcn_s_barrier();
            QKV_STAGE(cur, (kb + 2) * 64);
        }
    }
#undef QKV_STAGE

    // epilogue: per ni, tensor = (nw+ni*16)>>6 is wave-uniform
    const int b = m0 >> 8, tbase = m0 & 255;
    unsigned short* qkbase[2] = {
        Qo + (size_t)((b * Hn + h) * Tn) * Dn,
        Ko + (size_t)((b * Hn + h) * Tn) * Dn };
    unsigned short* vdst = Vt + (size_t)((b * Hn + h) * Dn) * Tn;
#pragma unroll
    for (int ni = 0; ni < 6; ++ni) {
        const int ng = nw + ni * 16;
        const int tensor = ng >> 6;
        const int d = (ng & 63) + l16;
        if (tensor < 2) {
            unsigned short* dst = qkbase[tensor];
#pragma unroll
            for (int mi = 0; mi < 4; ++mi)
#pragma unroll
                for (int r = 0; r < 4; ++r) {
                    int t = tbase + mw + mi * 16 + quad * 4 + r;
                    dst[t * Dn + d] = f2bf(acc[mi][ni][r]);
                }
        } else {
#pragma unroll
            for (int mi = 0; mi < 4; ++mi) {
                int t0 = tbase + mw + mi * 16 + quad * 4;
                ushort4 pk;
                pk.x = f2bf(acc[mi][ni][0]);
                pk.y = f2bf(acc[mi][ni][1]);
                pk.z = f2bf(acc[mi][ni][2]);
                pk.w = f2bf(acc[mi][ni][3]);
                *(ushort4*)&vdst[d * Tn + t0] = pk;
            }
        }
    }
}

// ---------------------------------------------------------------- attention (flash-style)
// grid (H, B): one block per (b,h). 4 waves, 256 threads.
// K[256][64] and V^T[64][256] staged in LDS once (XOR-swizzled), then
// barrier-free: wave w handles q-row-16-groups {w, 7-w, 8+w, 15-w}.
// Q frags for all 4 groups loaded BEFORE the barrier; setprio on MFMA.
__global__ __launch_bounds__(256) void attn_kernel(
    const unsigned short* __restrict__ Q, const unsigned short* __restrict__ K,
    const unsigned short* __restrict__ Vt, unsigned short* __restrict__ attout) {
    __shared__ unsigned short Kt[256][64];     // 32 KB, slot ^= (t&7)
    __shared__ unsigned short Vl[64][256];     // 32 KB, slot ^= (d&7)
    __shared__ unsigned short P[4][16][72];    // 9 KB, per-wave P / O staging

    const int h = blockIdx.x, b = blockIdx.y;
    const unsigned short* Qb = Q + (size_t)((b * Hn + h) * Tn) * Dn;
    const unsigned short* Kb = K + (size_t)((b * Hn + h) * Tn) * Dn;
    const unsigned short* Vb = Vt + (size_t)((b * Hn + h) * Dn) * Tn;

    const int tid = threadIdx.x;
    const int wave = tid >> 6, lane = tid & 63;
    const int quad = lane >> 4, l16 = lane & 15;

    const int grp[4] = {wave, 7 - wave, 8 + wave, 15 - wave};

    {
        const unsigned short* kg = Kb + (size_t)(lane >> 3) * Dn + ((lane & 7) ^ (lane >> 3)) * 8;
#pragma unroll
        for (int i = 0; i < 8; ++i) {
            const int c = wave * 8 + i;
            glds16(kg + (size_t)c * 8 * Dn, &Kt[c * 8][0]);
        }
#pragma unroll
        for (int i = 0; i < 8; ++i) {
            const int c = wave * 8 + i;
            const int d = c * 2 + (lane >> 5);
            const int j = (lane & 31) ^ (d & 7);
            glds16(Vb + (size_t)d * Tn + j * 8, &Vl[c * 2][0]);
        }
    }

    // hoist Q for all 4 groups: loads in flight under the staging DMA above
    bf16x8 aq[4][2];
#pragma unroll
    for (int gi = 0; gi < 4; ++gi) {
        const int q0 = grp[gi] * 16;
#pragma unroll
        for (int ks = 0; ks < 2; ++ks)
            aq[gi][ks] = *(const bf16x8*)&Qb[(q0 + l16) * Dn + ks * 32 + quad * 8];
    }

    __syncthreads();   // only barrier: K/V resident for the whole block

    const float cexp = 0.125f * 1.44269504f;   // scale * log2(e)

#pragma unroll
    for (int gi = 0; gi < 4; ++gi) {
        const int g = grp[gi];
        const int q0 = g * 16;

        f32x4 O[4];
#pragma unroll
        for (int i = 0; i < 4; ++i) O[i] = (f32x4){0.f, 0.f, 0.f, 0.f};
        float rsum[4] = {0.f, 0.f, 0.f, 0.f};

        const int ktmax = g >> 2;              // wave-uniform
        for (int kt = 0; kt <= ktmax; ++kt) {
            f32x4 S[4];
#pragma unroll
            for (int i = 0; i < 4; ++i) S[i] = (f32x4){0.f, 0.f, 0.f, 0.f};
            __builtin_amdgcn_s_setprio(1);
#pragma unroll
            for (int ks = 0; ks < 2; ++ks)
#pragma unroll
                for (int ni = 0; ni < 4; ++ni) {
                    bf16x8 bk = *(const bf16x8*)
                        &Kt[kt * 64 + ni * 16 + l16][(((ks * 4 + quad) ^ (l16 & 7)) * 8)];
                    S[ni] = mfma16(aq[gi][ks], bk, S[ni]);
                }
            __builtin_amdgcn_s_setprio(0);

#pragma unroll
            for (int ni = 0; ni < 4; ++ni)
#pragma unroll
                for (int r = 0; r < 4; ++r) {
                    int col = kt * 64 + ni * 16 + l16;
                    float p = exp2f(S[ni][r] * cexp);
                    p = (col > q0 + quad * 4 + r) ? 0.f : p;
                    rsum[r] += p;
                    P[wave][quad * 4 + r][ni * 16 + l16] = f2bf(p);
                }

            __builtin_amdgcn_s_setprio(1);
#pragma unroll
            for (int ks = 0; ks < 2; ++ks) {
                bf16x8 ap = *(const bf16x8*)&P[wave][l16][ks * 32 + quad * 8];
#pragma unroll
                for (int ni = 0; ni < 4; ++ni) {
                    bf16x8 bv = *(const bf16x8*)
                        &Vl[ni * 16 + l16][(((kt * 8 + ks * 4 + quad) ^ (l16 & 7)) * 8)];
                    O[ni] = mfma16(ap, bv, O[ni]);
                }
            }
            __builtin_amdgcn_s_setprio(0);
        }

#pragma unroll
        for (int r = 0; r < 4; ++r) {
            float s = rsum[r];
            s += __shfl_xor(s, 1);
            s += __shfl_xor(s, 2);
            s += __shfl_xor(s, 4);
            s += __shfl_xor(s, 8);
            rsum[r] = s;
        }

#pragma unroll
        for (int r = 0; r < 4; ++r) {
            float inv = 1.0f / rsum[r];
#pragma unroll
            for (int ni = 0; ni < 4; ++ni)
                P[wave][quad * 4 + r][ni * 16 + l16] = f2bf(O[ni][r] * inv);
        }
        const int row = lane >> 2;             // 0..15
        const int colc = (lane & 3) * 16;      // 0,16,32,48
        unsigned short* dst = attout + (size_t)(b * Tn + q0 + row) * (Hn * Dn) + h * Dn + colc;
        *(uint4*)dst = *(const uint4*)&P[wave][row][colc];
        *(uint4*)(dst + 8) = *(const uint4*)&P[wave][row][colc + 8];
    }
}

// ---------------------------------------------------------------- output projection
// grid 1536 (flattened, XCD swizzle; n fast). 128x128 tile, double-buffered,
// counted vmcnt (per-wave loads/tile = 8). No setprio (GEMM-negative, r7).
__global__ __launch_bounds__(256) void proj_gemm(
    const unsigned short* __restrict__ attout, const unsigned short* __restrict__ wpt,
    const float* __restrict__ bproj, float* __restrict__ out) {
    __shared__ unsigned short As[2][128][64];   // 32 KB
    __shared__ unsigned short Bs[2][128][64];   // 32 KB (64 KB total, 2 blk/CU)

    const int bid = blockIdx.x;
    const int swz = (bid & 7) * 192 + (bid >> 3);   // 1536/8 = 192, bijective
    const int n0 = (swz % 3) * 128;
    const int m0 = (swz / 3) * 128;

    const int tid = threadIdx.x;
    const int wave = tid >> 6, lane = tid & 63;
    const int quad = lane >> 4, l16 = lane & 15;
    const int mw = (wave >> 1) * 64, nw = (wave & 1) * 64;

    f32x4 acc[4][4];
#pragma unroll
    for (int i = 0; i < 4; ++i)
#pragma unroll
        for (int j = 0; j < 4; ++j) acc[i][j] = (f32x4){0.f, 0.f, 0.f, 0.f};

    const int lr = lane >> 3;
    const int js = (lane & 7) ^ lr;

    const unsigned short* ga[4];
    const unsigned short* gb[4];
#pragma unroll
    for (int i = 0; i < 4; ++i) {
        ga[i] = attout + (size_t)(m0 + wave * 32 + i * 8 + lr) * En + js * 8;
        gb[i] = wpt + (size_t)(n0 + wave * 32 + i * 8 + lr) * En + js * 8;
    }

#define PROJ_STAGE(buf, koff)                                             \
    do {                                                                  \
        _Pragma("unroll") for (int i = 0; i < 4; ++i)                     \
            glds16(ga[i] + (koff), &As[buf][wave * 32 + i * 8][0]);       \
        _Pragma("unroll") for (int i = 0; i < 4; ++i)                     \
            glds16(gb[i] + (koff), &Bs[buf][wave * 32 + i * 8][0]);       \
    } while (0)

    PROJ_STAGE(0, 0);
    PROJ_STAGE(1, 64);

#pragma unroll
    for (int kb = 0; kb < 6; ++kb) {
        if (kb < 5) asm volatile("s_waitcnt vmcnt(8)" ::: "memory");
        else        asm volatile("s_waitcnt vmcnt(0)" ::: "memory");
        __builtin_amdgcn_s_barrier();

        const int cur = kb & 1;
#pragma unroll
        for (int ks = 0; ks < 2; ++ks) {
            bf16x8 a[4], bb[4];
            const int ps = ((ks * 4 + quad) ^ (l16 & 7)) * 8;
#pragma unroll
            for (int mi = 0; mi < 4; ++mi)
                a[mi] = *(const bf16x8*)&As[cur][mw + mi * 16 + l16][ps];
#pragma unroll
            for (int ni = 0; ni < 4; ++ni)
                bb[ni] = *(const bf16x8*)&Bs[cur][nw + ni * 16 + l16][ps];
#pragma unroll
            for (int mi = 0; mi < 4; ++mi)
#pragma unroll
                for (int ni = 0; ni < 4; ++ni) acc[mi][ni] = mfma16(a[mi], bb[ni], acc[mi][ni]);
        }

        if (kb < 4) {
            __builtin_amdgcn_s_barrier();
            PROJ_STAGE(cur, (kb + 2) * 64);
        }
    }
#undef PROJ_STAGE

#pragma unroll
    for (int mi = 0; mi < 4; ++mi)
#pragma unroll
        for (int ni = 0; ni < 4; ++ni)
#pragma unroll
            for (int r = 0; r < 4; ++r) {
                int row = m0 + mw + mi * 16 + quad * 4 + r;
                int col = n0 + nw + ni * 16 + l16;
                out[(size_t)row * En + col] = acc[mi][ni][r] + bproj[col];
            }
}

// ---------------------------------------------------------------- launch
extern "C" void kernel_launch(void* const* d_in, const int* in_sizes, int n_in,
                              void* d_out, int out_size, void* d_ws, size_t ws_size,
                              hipStream_t stream) {
    const float* x  = (const float*)d_in[0];
    const float* wq = (const float*)d_in[1];
    const float* wk = (const float*)d_in[2];
    const float* wv = (const float*)d_in[3];
    const float* wp = (const float*)d_in[4];
    const float* bp = (const float*)d_in[5];
    float* out = (float*)d_out;

    char* ws = (char*)d_ws;
    const size_t WT_OFF  = 0;                                  // 884736
    const size_t WPT_OFF = WT_OFF + 884736;                    // 294912
    const size_t Q_OFF   = WPT_OFF + 294912;                   // 50331648 each below
    const size_t K_OFF   = Q_OFF + 50331648ull;
    const size_t VT_OFF  = K_OFF + 50331648ull;
    const size_t XB_OFF  = VT_OFF + 50331648ull;               // xb; attout aliases this

    unsigned short* wt   = (unsigned short*)(ws + WT_OFF);
    unsigned short* wpt  = (unsigned short*)(ws + WPT_OFF);
    unsigned short* Qd   = (unsigned short*)(ws + Q_OFF);
    unsigned short* Kd   = (unsigned short*)(ws + K_OFF);
    unsigned short* Vtd  = (unsigned short*)(ws + VT_OFF);
    unsigned short* xbd  = (unsigned short*)(ws + XB_OFF);
    unsigned short* ao   = xbd;   // xb dead after qkv_gemm; attn overwrites it

    prep_xcast_kernel<<<14592, 256, 0, stream>>>(wq, wk, wv, wp, x, wt, wpt, xbd);
    qkv_gemm<<<3072, 256, 0, stream>>>(xbd, wt, Qd, Kd, Vtd);
    attn_kernel<<<dim3(Hn, Bn), 256, 0, stream>>>(Qd, Kd, Vtd, ao);
    proj_gemm<<<1536, 256, 0, stream>>>(ao, wpt, bp, out);
}

// Round 11
// 334.555 us; speedup vs baseline: 1.0773x; 1.0411x over previous
//
#include <hip/hip_runtime.h>
#include <hip/hip_bf16.h>

// MHA: B=256, T=256, E=384, H=6, D=64.  fp32 in/out, bf16 MFMA internally.
//
//   prep+xcast: fused: blocks [0,12288) cast x->bf16, rest repack weights.
//   qkv:   round-6 form (77 us measured): BK=64 double-buffered LDS,
//          counted vmcnt(10), raw s_barrier pair per step, glds16 staging,
//          T21 both-sides XOR swizzle (0 conflicts), bijective XCD swizzle.
//          NO setprio (round-7 A/B: -6 us on this GEMM structure).
//   attn:  ROUND 11: 512 threads / 8 waves, wave w owns q-groups {w, 15-w}
//          (exactly 5 kt-iters per wave). P per-wave [16][64] XOR-swizzled
//          (no pad) -> LDS exactly 80 KB -> 2 blk/CU -> 16 waves/CU (2x TLP
//          vs round-7's 8). Causal mask only on the last kt-tile (interior
//          tiles provably unmasked). Q hoisted pre-barrier; setprio on MFMA.
//   proj:  round-6 form (BK=64 dbuf counted vmcnt, no setprio).
//
//   Round-9 lesson: qkv+attn mega-fusion = 164 us (barrier-bound, 1 blk/CU);
//   traffic savings are irrelevant in the latency-bound regime.

#define Bn 256
#define Tn 256
#define En 384
#define Hn 6
#define Dn 64

typedef __bf16 bf16x8 __attribute__((ext_vector_type(8)));
typedef float f32x4 __attribute__((ext_vector_type(4)));
typedef unsigned short u16x8 __attribute__((ext_vector_type(8)));

static __device__ __forceinline__ unsigned short f2bf(float f) {
    unsigned int u = __builtin_bit_cast(unsigned int, f);
    u += 0x7fffu + ((u >> 16) & 1u);   // RNE
    return (unsigned short)(u >> 16);
}

static __device__ __forceinline__ f32x4 mfma16(bf16x8 a, bf16x8 b, f32x4 c) {
    return __builtin_amdgcn_mfma_f32_16x16x32_bf16(a, b, c, 0, 0, 0);
}

// async global->LDS, 16 B per lane. LDS dest = wave-uniform base + lane*16.
static __device__ __forceinline__ void glds16(const unsigned short* g, unsigned short* l) {
    __builtin_amdgcn_global_load_lds(
        (const __attribute__((address_space(1))) unsigned int*)g,
        (__attribute__((address_space(3))) unsigned int*)l, 16, 0, 0);
}

// ---------------------------------------------------------------- prep + xcast (fused)
__global__ __launch_bounds__(256) void prep_xcast_kernel(
    const float* __restrict__ wq, const float* __restrict__ wk,
    const float* __restrict__ wv, const float* __restrict__ wp,
    const float* __restrict__ x,
    unsigned short* __restrict__ wt, unsigned short* __restrict__ wpt,
    unsigned short* __restrict__ xb) {
    const int bid = blockIdx.x;
    if (bid < 12288) {
        size_t i = ((size_t)bid * 256 + threadIdx.x) * 8;
        float4 f0 = *(const float4*)(x + i);
        float4 f1 = *(const float4*)(x + i + 4);
        u16x8 p;
        p[0] = f2bf(f0.x); p[1] = f2bf(f0.y); p[2] = f2bf(f0.z); p[3] = f2bf(f0.w);
        p[4] = f2bf(f1.x); p[5] = f2bf(f1.y); p[6] = f2bf(f1.z); p[7] = f2bf(f1.w);
        *(u16x8*)(xb + i) = p;
    } else {
        const int NW = 3 * Hn * Dn * En;      // 442368
        const int NP = En * En;               // 147456
        int idx = (bid - 12288) * 256 + threadIdx.x;
        if (idx < NW) {
            int e = idx % En;
            int d = (idx / En) % Dn;
            int h = (idx / (En * Dn)) % Hn;
            int t = idx / (En * Dn * Hn);
            const float* src = (t == 0) ? wq : (t == 1) ? wk : wv;
            wt[idx] = f2bf(src[(h * En + e) * Dn + d]);
        } else if (idx < NW + NP) {
            int j = idx - NW;
            int k = j % En;
            int n = j / En;
            wpt[j] = f2bf(wp[k * En + n]);
        }
    }
}

// ---------------------------------------------------------------- QKV projection (merged)
// grid 3072 (flattened): bijective XCD swizzle; logical order = head-fast.
// Tile 128x192, 4 waves 2x2, wave 64x96 (acc[4][6]).
// Double-buffered LDS, counted vmcnt (per-wave loads/tile = 4 A + 6 B = 10).
__global__ __launch_bounds__(256) void qkv_gemm(
    const unsigned short* __restrict__ xb, const unsigned short* __restrict__ wt,
    unsigned short* __restrict__ Qo, unsigned short* __restrict__ Ko,
    unsigned short* __restrict__ Vt) {
    __shared__ unsigned short As[2][128][64];   // 32 KB
    __shared__ unsigned short Bs[2][192][64];   // 48 KB  (80 KB total, 2 blk/CU)

    const int bid = blockIdx.x;
    const int swz = (bid & 7) * 384 + (bid >> 3);   // 3072/8 = 384, bijective
    const int h = swz % Hn;
    const int m0 = (swz / Hn) * 128;

    const int tid = threadIdx.x;
    const int wave = tid >> 6, lane = tid & 63;
    const int quad = lane >> 4, l16 = lane & 15;
    const int mw = (wave >> 1) * 64, nw = (wave & 1) * 96;

    f32x4 acc[4][6];
#pragma unroll
    for (int i = 0; i < 4; ++i)
#pragma unroll
        for (int j = 0; j < 6; ++j) acc[i][j] = (f32x4){0.f, 0.f, 0.f, 0.f};

    // staging geometry: chunk = 8 rows x 64 cols (1 KB = 64 lanes x 16 B).
    // lane l -> row 8k + (l>>3), physical 16B-slot l&7.
    // pre-swizzled source: logical slot j = (l&7) ^ (l>>3)  (row&7 == l>>3).
    const int lr = lane >> 3;
    const int js = (lane & 7) ^ lr;

    const unsigned short* ga[4];
#pragma unroll
    for (int i = 0; i < 4; ++i)
        ga[i] = xb + (size_t)(m0 + wave * 32 + i * 8 + lr) * En + js * 8;
    const unsigned short* gb[6];
#pragma unroll
    for (int i = 0; i < 6; ++i) {
        int n = wave * 48 + i * 8 + lr;
        gb[i] = wt + (size_t)(((n >> 6) * Hn + h) * Dn + (n & 63)) * En + js * 8;
    }

#define QKV_STAGE(buf, koff)                                              \
    do {                                                                  \
        _Pragma("unroll") for (int i = 0; i < 4; ++i)                     \
            glds16(ga[i] + (koff), &As[buf][wave * 32 + i * 8][0]);       \
        _Pragma("unroll") for (int i = 0; i < 6; ++i)                     \
            glds16(gb[i] + (koff), &Bs[buf][wave * 48 + i * 8][0]);       \
    } while (0)

    QKV_STAGE(0, 0);
    QKV_STAGE(1, 64);

#pragma unroll
    for (int kb = 0; kb < 6; ++kb) {
        // wait for tile kb's own 10 loads only (tile kb+1's stay in flight)
        if (kb < 5) asm volatile("s_waitcnt vmcnt(10)" ::: "memory");
        else        asm volatile("s_waitcnt vmcnt(0)" ::: "memory");
        __builtin_amdgcn_s_barrier();   // raw: no vmcnt(0) drain

        const int cur = kb & 1;
#pragma unroll
        for (int ks = 0; ks < 2; ++ks) {
            bf16x8 a[4], b[6];
            const int ps = ((ks * 4 + quad) ^ (l16 & 7)) * 8;  // swizzled slot
#pragma unroll
            for (int mi = 0; mi < 4; ++mi)
                a[mi] = *(const bf16x8*)&As[cur][mw + mi * 16 + l16][ps];
#pragma unroll
            for (int ni = 0; ni < 6; ++ni)
                b[ni] = *(const bf16x8*)&Bs[cur][nw + ni * 16 + l16][ps];
#pragma unroll
            for (int mi = 0; mi < 4; ++mi)
#pragma unroll
                for (int ni = 0; ni < 6; ++ni) acc[mi][ni] = mfma16(a[mi], b[ni], acc[mi][ni]);
        }

        if (kb < 4) {
            // all waves done reading buf[cur] before its DMA overwrite
            __builtin_amdgcn_s_barrier();
            QKV_STAGE(cur, (kb + 2) * 64);
        }
    }
#undef QKV_STAGE

    // epilogue: per ni, tensor = (nw+ni*16)>>6 is wave-uniform
    const int b = m0 >> 8, tbase = m0 & 255;
    unsigned short* qkbase[2] = {
        Qo + (size_t)((b * Hn + h) * Tn) * Dn,
        Ko + (size_t)((b * Hn + h) * Tn) * Dn };
    unsigned short* vdst = Vt + (size_t)((b * Hn + h) * Dn) * Tn;
#pragma unroll
    for (int ni = 0; ni < 6; ++ni) {
        const int ng = nw + ni * 16;
        const int tensor = ng >> 6;
        const int d = (ng & 63) + l16;
        if (tensor < 2) {
            unsigned short* dst = qkbase[tensor];
#pragma unroll
            for (int mi = 0; mi < 4; ++mi)
#pragma unroll
                for (int r = 0; r < 4; ++r) {
                    int t = tbase + mw + mi * 16 + quad * 4 + r;
                    dst[t * Dn + d] = f2bf(acc[mi][ni][r]);
                }
        } else {
#pragma unroll
            for (int mi = 0; mi < 4; ++mi) {
                int t0 = tbase + mw + mi * 16 + quad * 4;
                ushort4 pk;
                pk.x = f2bf(acc[mi][ni][0]);
                pk.y = f2bf(acc[mi][ni][1]);
                pk.z = f2bf(acc[mi][ni][2]);
                pk.w = f2bf(acc[mi][ni][3]);
                *(ushort4*)&vdst[d * Tn + t0] = pk;
            }
        }
    }
}

// ---------------------------------------------------------------- attention (flash-style)
// grid (H, B), 512 threads / 8 waves. K[256][64] + V^T[64][256] staged once
// (XOR-swizzled glds16), then barrier-free: wave w owns q-groups {w, 15-w}
// (exactly 5 kt-iters each). P: per-wave [16][64], slot-XOR swizzled (no pad)
// -> LDS = 32+32+16 = 80 KB exactly -> 2 blk/CU -> 16 waves/CU.
// Causal mask applied only on the last kt-tile of each group.
__global__ __launch_bounds__(512, 4) void attn_kernel(
    const unsigned short* __restrict__ Q, const unsigned short* __restrict__ K,
    const unsigned short* __restrict__ Vt, unsigned short* __restrict__ attout) {
    __shared__ unsigned short Kt[256][64];     // 32 KB, slot ^= (t&7)
    __shared__ unsigned short Vl[64][256];     // 32 KB, slot ^= (d&7)
    __shared__ unsigned short P[8][16][64];    // 16 KB, per-wave, slot ^= (row&7)

    const int h = blockIdx.x, b = blockIdx.y;
    const unsigned short* Qb = Q + (size_t)((b * Hn + h) * Tn) * Dn;
    const unsigned short* Kb = K + (size_t)((b * Hn + h) * Tn) * Dn;
    const unsigned short* Vb = Vt + (size_t)((b * Hn + h) * Dn) * Tn;

    const int tid = threadIdx.x;
    const int wave = tid >> 6, lane = tid & 63;
    const int quad = lane >> 4, l16 = lane & 15;

    const int grp[2] = {wave, 15 - wave};

    // ---- stage K (32 chunks of 8x64) and V (32 chunks of 2x256), 4+4 per wave
    {
        const unsigned short* kg = Kb + (size_t)(lane >> 3) * Dn + ((lane & 7) ^ (lane >> 3)) * 8;
#pragma unroll
        for (int i = 0; i < 4; ++i) {
            const int c = wave * 4 + i;
            glds16(kg + (size_t)c * 8 * Dn, &Kt[c * 8][0]);
        }
#pragma unroll
        for (int i = 0; i < 4; ++i) {
            const int c = wave * 4 + i;
            const int d = c * 2 + (lane >> 5);
            const int j = (lane & 31) ^ (d & 7);
            glds16(Vb + (size_t)d * Tn + j * 8, &Vl[c * 2][0]);
        }
    }

    // hoist Q for both groups: loads in flight under the staging DMA above
    bf16x8 aq[2][2];
#pragma unroll
    for (int gi = 0; gi < 2; ++gi) {
        const int q0 = grp[gi] * 16;
#pragma unroll
        for (int ks = 0; ks < 2; ++ks)
            aq[gi][ks] = *(const bf16x8*)&Qb[(q0 + l16) * Dn + ks * 32 + quad * 8];
    }

    __syncthreads();   // only barrier: K/V resident for the whole block

    const float cexp = 0.125f * 1.44269504f;   // scale * log2(e)

#pragma unroll
    for (int gi = 0; gi < 2; ++gi) {
        const int g = grp[gi];
        const int q0 = g * 16;

        f32x4 O[4];
#pragma unroll
        for (int i = 0; i < 4; ++i) O[i] = (f32x4){0.f, 0.f, 0.f, 0.f};
        float rsum[4] = {0.f, 0.f, 0.f, 0.f};

        const int ktmax = g >> 2;              // wave-uniform
        for (int kt = 0; kt <= ktmax; ++kt) {
            f32x4 S[4];
#pragma unroll
            for (int i = 0; i < 4; ++i) S[i] = (f32x4){0.f, 0.f, 0.f, 0.f};
            __builtin_amdgcn_s_setprio(1);
#pragma unroll
            for (int ks = 0; ks < 2; ++ks)
#pragma unroll
                for (int ni = 0; ni < 4; ++ni) {
                    bf16x8 bk = *(const bf16x8*)
                        &Kt[kt * 64 + ni * 16 + l16][(((ks * 4 + quad) ^ (l16 & 7)) * 8)];
                    S[ni] = mfma16(aq[gi][ks], bk, S[ni]);
                }
            __builtin_amdgcn_s_setprio(0);

            // exp + row-sum + P. Mask only on the final tile (interior tiles
            // satisfy col <= row by construction). P write: row t=quad*4+r,
            // col c=ni*16+l16 -> P[w][t][((c>>3)^(t&7))*8 + (c&7)].
            const bool last = (kt == ktmax);   // wave-uniform branch
#pragma unroll
            for (int ni = 0; ni < 4; ++ni)
#pragma unroll
                for (int r = 0; r < 4; ++r) {
                    const int t = quad * 4 + r;
                    float p = exp2f(S[ni][r] * cexp);
                    if (last) {
                        int col = kt * 64 + ni * 16 + l16;
                        p = (col > q0 + t) ? 0.f : p;
                    }
                    rsum[r] += p;
                    P[wave][t][(((ni * 2 + (l16 >> 3)) ^ (t & 7)) << 3) + (l16 & 7)] = f2bf(p);
                }

            __builtin_amdgcn_s_setprio(1);
#pragma unroll
            for (int ks = 0; ks < 2; ++ks) {
                bf16x8 ap = *(const bf16x8*)
                    &P[wave][l16][(((ks * 4 + quad) ^ (l16 & 7)) * 8)];
#pragma unroll
                for (int ni = 0; ni < 4; ++ni) {
                    bf16x8 bv = *(const bf16x8*)
                        &Vl[ni * 16 + l16][(((kt * 8 + ks * 4 + quad) ^ (l16 & 7)) * 8)];
                    O[ni] = mfma16(ap, bv, O[ni]);
                }
            }
            __builtin_amdgcn_s_setprio(0);
        }

        // reduce row sums across the 16 lanes holding each row
#pragma unroll
        for (int r = 0; r < 4; ++r) {
            float s = rsum[r];
            s += __shfl_xor(s, 1);
            s += __shfl_xor(s, 2);
            s += __shfl_xor(s, 4);
            s += __shfl_xor(s, 8);
            rsum[r] = s;
        }

        // stage O in P[wave] (same swizzled mapping), then coalesced 16B stores
#pragma unroll
        for (int r = 0; r < 4; ++r) {
            const int t = quad * 4 + r;
            float inv = 1.0f / rsum[r];
#pragma unroll
            for (int ni = 0; ni < 4; ++ni)
                P[wave][t][(((ni * 2 + (l16 >> 3)) ^ (t & 7)) << 3) + (l16 & 7)] =
                    f2bf(O[ni][r] * inv);
        }
        const int row = lane >> 2;             // 0..15
        const int colc = (lane & 3) * 16;      // 0,16,32,48
        const int s0 = (colc >> 3) ^ (row & 7);
        const int s1 = ((colc >> 3) + 1) ^ (row & 7);
        unsigned short* dst = attout + (size_t)(b * Tn + q0 + row) * (Hn * Dn) + h * Dn + colc;
        *(uint4*)dst = *(const uint4*)&P[wave][row][s0 * 8];
        *(uint4*)(dst + 8) = *(const uint4*)&P[wave][row][s1 * 8];
    }
}

// ---------------------------------------------------------------- output projection
// grid 1536 (flattened, XCD swizzle; n fast). 128x128 tile, double-buffered,
// counted vmcnt (per-wave loads/tile = 8).
__global__ __launch_bounds__(256) void proj_gemm(
    const unsigned short* __restrict__ attout, const unsigned short* __restrict__ wpt,
    const float* __restrict__ bproj, float* __restrict__ out) {
    __shared__ unsigned short As[2][128][64];   // 32 KB
    __shared__ unsigned short Bs[2][128][64];   // 32 KB (64 KB total, 2 blk/CU)

    const int bid = blockIdx.x;
    const int swz = (bid & 7) * 192 + (bid >> 3);   // 1536/8 = 192, bijective
    const int n0 = (swz % 3) * 128;
    const int m0 = (swz / 3) * 128;

    const int tid = threadIdx.x;
    const int wave = tid >> 6, lane = tid & 63;
    const int quad = lane >> 4, l16 = lane & 15;
    const int mw = (wave >> 1) * 64, nw = (wave & 1) * 64;

    f32x4 acc[4][4];
#pragma unroll
    for (int i = 0; i < 4; ++i)
#pragma unroll
        for (int j = 0; j < 4; ++j) acc[i][j] = (f32x4){0.f, 0.f, 0.f, 0.f};

    const int lr = lane >> 3;
    const int js = (lane & 7) ^ lr;

    const unsigned short* ga[4];
    const unsigned short* gb[4];
#pragma unroll
    for (int i = 0; i < 4; ++i) {
        ga[i] = attout + (size_t)(m0 + wave * 32 + i * 8 + lr) * En + js * 8;
        gb[i] = wpt + (size_t)(n0 + wave * 32 + i * 8 + lr) * En + js * 8;
    }

#define PROJ_STAGE(buf, koff)                                             \
    do {                                                                  \
        _Pragma("unroll") for (int i = 0; i < 4; ++i)                     \
            glds16(ga[i] + (koff), &As[buf][wave * 32 + i * 8][0]);       \
        _Pragma("unroll") for (int i = 0; i < 4; ++i)                     \
            glds16(gb[i] + (koff), &Bs[buf][wave * 32 + i * 8][0]);       \
    } while (0)

    PROJ_STAGE(0, 0);
    PROJ_STAGE(1, 64);

#pragma unroll
    for (int kb = 0; kb < 6; ++kb) {
        if (kb < 5) asm volatile("s_waitcnt vmcnt(8)" ::: "memory");
        else        asm volatile("s_waitcnt vmcnt(0)" ::: "memory");
        __builtin_amdgcn_s_barrier();

        const int cur = kb & 1;
#pragma unroll
        for (int ks = 0; ks < 2; ++ks) {
            bf16x8 a[4], bb[4];
            const int ps = ((ks * 4 + quad) ^ (l16 & 7)) * 8;
#pragma unroll
            for (int mi = 0; mi < 4; ++mi)
                a[mi] = *(const bf16x8*)&As[cur][mw + mi * 16 + l16][ps];
#pragma unroll
            for (int ni = 0; ni < 4; ++ni)
                bb[ni] = *(const bf16x8*)&Bs[cur][nw + ni * 16 + l16][ps];
#pragma unroll
            for (int mi = 0; mi < 4; ++mi)
#pragma unroll
                for (int ni = 0; ni < 4; ++ni) acc[mi][ni] = mfma16(a[mi], bb[ni], acc[mi][ni]);
        }

        if (kb < 4) {
            __builtin_amdgcn_s_barrier();
            PROJ_STAGE(cur, (kb + 2) * 64);
        }
    }
#undef PROJ_STAGE

#pragma unroll
    for (int mi = 0; mi < 4; ++mi)
#pragma unroll
        for (int ni = 0; ni < 4; ++ni)
#pragma unroll
            for (int r = 0; r < 4; ++r) {
                int row = m0 + mw + mi * 16 + quad * 4 + r;
                int col = n0 + nw + ni * 16 + l16;
                out[(size_t)row * En + col] = acc[mi][ni][r] + bproj[col];
            }
}

// ---------------------------------------------------------------- launch
extern "C" void kernel_launch(void* const* d_in, const int* in_sizes, int n_in,
                              void* d_out, int out_size, void* d_ws, size_t ws_size,
                              hipStream_t stream) {
    const float* x  = (const float*)d_in[0];
    const float* wq = (const float*)d_in[1];
    const float* wk = (const float*)d_in[2];
    const float* wv = (const float*)d_in[3];
    const float* wp = (const float*)d_in[4];
    const float* bp = (const float*)d_in[5];
    float* out = (float*)d_out;

    char* ws = (char*)d_ws;
    const size_t WT_OFF  = 0;                                  // 884736
    const size_t WPT_OFF = WT_OFF + 884736;                    // 294912
    const size_t Q_OFF   = WPT_OFF + 294912;                   // 50331648 each below
    const size_t K_OFF   = Q_OFF + 50331648ull;
    const size_t VT_OFF  = K_OFF + 50331648ull;
    const size_t XB_OFF  = VT_OFF + 50331648ull;               // xb; attout aliases this

    unsigned short* wt   = (unsigned short*)(ws + WT_OFF);
    unsigned short* wpt  = (unsigned short*)(ws + WPT_OFF);
    unsigned short* Qd   = (unsigned short*)(ws + Q_OFF);
    unsigned short* Kd   = (unsigned short*)(ws + K_OFF);
    unsigned short* Vtd  = (unsigned short*)(ws + VT_OFF);
    unsigned short* xbd  = (unsigned short*)(ws + XB_OFF);
    unsigned short* ao   = xbd;   // xb dead after qkv_gemm; attn overwrites it

    prep_xcast_kernel<<<14592, 256, 0, stream>>>(wq, wk, wv, wp, x, wt, wpt, xbd);
    qkv_gemm<<<3072, 256, 0, stream>>>(xbd, wt, Qd, Kd, Vtd);
    attn_kernel<<<dim3(Hn, Bn), 512, 0, stream>>>(Qd, Kd, Vtd, ao);
    proj_gemm<<<1536, 256, 0, stream>>>(ao, wpt, bp, out);
}